// Round 4
// baseline (95.294 us; speedup 1.0000x reference)
//
#include <hip/hip_runtime.h>

// MTCNN proposal stage: score threshold + greedy NMS + bbox regression, 96x96.
//
// Validated-exact facts (R1-R3 passed, absmax 0.0):
//  - All boxes 21x21 (area 441), pitch 3/4/3 (period 3). IoU>0.5 <=> inter>294.
//  - Suppression pairs only at 12 offsets {+-1,+-2 axial, +-1 diagonal} with an
//    index%3 geometry rule => pure bit logic, no float IoU.
//  - Greedy NMS == unique fixpoint of monotone 3-state relaxation over the
//    dominance graph (priority = score desc, index asc; ties on negative
//    offsets use >=). In-place bitboard Jacobi is race-benign (decisions
//    final, per-bit monotone).
//
// R4: (1) kernel split — single-block NMS writes a 144-word keep bitmap to
// d_ws; a 36-block kernel does the memory-heavy epilogue in parallel.
// (2) activity-gated rounds — per-word changed bitmap (ballot, ping-pong,
// 1 barrier/round); a word re-evaluates only if its +-3-word window changed
// last round. Sound: a cell becomes resolvable only in the round after a
// window word changes; round 0 is all-active.

namespace {

constexpr int Hh = 96, Ww = 96, Nn = Hh * Ww;   // 9216
constexpr int NW = Nn / 64;                      // 144 words
constexpr float THR_SCORE = 0.6f;
constexpr int NTA = 256;                         // NMS kernel block
constexpr int NTB = 256;                         // epilogue block (36 blocks)

// Bit b -> flat offset: {-1,+1,-2,+2,-96,+96,-192,+192,-97,-95,+95,+97}
__device__ __forceinline__ unsigned long long shift_b(const unsigned long long w[9], int b) {
  // result bit i (word t) = bitmap bit (64*t + i + OFF[b]); w[j] = W[t-4+j]
  switch (b) {
    case 0:  return (w[4] << 1)  | (w[3] >> 63);   // -1
    case 1:  return (w[4] >> 1)  | (w[5] << 63);   // +1
    case 2:  return (w[4] << 2)  | (w[3] >> 62);   // -2
    case 3:  return (w[4] >> 2)  | (w[5] << 62);   // +2
    case 4:  return (w[3] << 32) | (w[2] >> 32);   // -96
    case 5:  return (w[5] >> 32) | (w[6] << 32);   // +96
    case 6:  return w[1];                          // -192
    case 7:  return w[7];                          // +192
    case 8:  return (w[3] << 33) | (w[2] >> 31);   // -97
    case 9:  return (w[3] << 31) | (w[2] >> 33);   // -95
    case 10: return (w[5] >> 31) | (w[6] << 33);   // +95
    default: return (w[5] >> 33) | (w[6] << 31);   // +97
  }
}

__global__ __launch_bounds__(NTA) void nms_kernel(
    const float* __restrict__ cls,
    unsigned long long* __restrict__ keep_out)
{
  __shared__ float s_sc[Nn];
  __shared__ unsigned long long s_D[12][NW];
  __shared__ unsigned long long s_Up[NW + 8];     // 4 guard words each side
  __shared__ unsigned long long s_Kp[NW + 8];
  __shared__ unsigned long long s_chg[2][5];      // [buf][1 guard | 3 words | 1 guard]

  unsigned long long* const U = s_Up + 4;
  unsigned long long* const K = s_Kp + 4;

  const int tid = threadIdx.x;
  const int lane = tid & 63;
  const int OFF[12] = {-1, 1, -2, 2, -Ww, Ww, -2*Ww, 2*Ww, -Ww-1, -Ww+1, Ww-1, Ww+1};

  // ---- Phase 1: stage scores, zero guards, init change flags ----
  for (int q = tid; q < Nn / 4; q += NTA)
    reinterpret_cast<float4*>(s_sc)[q] = reinterpret_cast<const float4*>(cls)[q];
  if (tid < 4) {
    s_Up[tid] = 0ull; s_Kp[tid] = 0ull;
    s_Up[4 + NW + tid] = 0ull; s_Kp[4 + NW + tid] = 0ull;
  }
  if (tid == 0) {
    s_chg[0][0] = 0ull; s_chg[0][4] = 0ull;
    s_chg[1][0] = 0ull; s_chg[1][4] = 0ull;
    s_chg[1][1] = ~0ull; s_chg[1][2] = ~0ull; s_chg[1][3] = ~0ull;  // round-0 prev: all active
  }
  __syncthreads();

  // ---- Phase 2: per-cell dominance mask (validated logic) -> ballots ----
  for (int n = tid; n < Nn; n += NTA) {
    float si = s_sc[n];
    unsigned int m = 0;
    bool valid = si > THR_SCORE;
    if (valid) {
      int r = n / Ww, c = n - r * Ww;
      int rm = r % 3, cm = c % 3;
      unsigned int geom = (1u << 0) | (1u << 1) | (1u << 4) | (1u << 5);
      if (cm == 1) geom |= 1u << 2;
      if (cm == 2) geom |= 1u << 3;
      if (rm == 1) geom |= 1u << 6;
      if (rm == 2) geom |= 1u << 7;
      if (!(rm == 2 && cm == 2)) geom |= 1u << 8;
      if (!(rm == 2 && cm == 1)) geom |= 1u << 9;
      if (!(rm == 1 && cm == 2)) geom |= 1u << 10;
      if (!(rm == 1 && cm == 1)) geom |= 1u << 11;
      unsigned int inb = 0;
      bool cge1 = c >= 1, cle = c <= Ww - 2, rge1 = r >= 1, rle = r <= Hh - 2;
      if (cge1) inb |= 1u << 0;
      if (cle)  inb |= 1u << 1;
      if (c >= 2)      inb |= 1u << 2;
      if (c <= Ww - 3) inb |= 1u << 3;
      if (rge1) inb |= 1u << 4;
      if (rle)  inb |= 1u << 5;
      if (r >= 2)      inb |= 1u << 6;
      if (r <= Hh - 3) inb |= 1u << 7;
      if (rge1 && cge1) inb |= 1u << 8;
      if (rge1 && cle)  inb |= 1u << 9;
      if (rle && cge1)  inb |= 1u << 10;
      if (rle && cle)   inb |= 1u << 11;
      unsigned int cand = geom & inb;
      #pragma unroll
      for (int b = 0; b < 12; ++b) {
        int j = n + OFF[b];
        j = min(max(j, 0), Nn - 1);
        float sj = s_sc[j];
        bool ge = (b == 0) | (b == 2) | (b == 4) | (b == 6) | (b == 8) | (b == 9);
        bool dom = ge ? (sj >= si) : (sj > si);
        if (((cand >> b) & 1u) && (sj > THR_SCORE) && dom) m |= 1u << b;
      }
    }
    int w = n >> 6;
    #pragma unroll
    for (int b = 0; b < 12; ++b) {
      unsigned long long bb = __ballot((m >> b) & 1u);
      if (lane == 0) s_D[b][w] = bb;
    }
    unsigned long long vb = __ballot(valid);
    if (lane == 0) { U[w] = vb; K[w] = 0ull; }
  }
  __syncthreads();

  // ---- Relaxation: activity-gated bitboard Jacobi, 1 barrier/round ----
  int cur = 0;   // buffer WRITTEN this round; prev = cur^1
  for (int it = 0; it < 5000; ++it) {
    if (tid < 192) {                       // waves 0-2 participate in ballot
      bool changed = false;
      const int t = tid;
      if (t < NW) {
        // window = prev-changed bits t-3..t+3 (guarded 128-bit extract)
        int sh = (t - 3) & 63;
        int wlo = (t + 61) >> 6;           // floor((t-3)/64) + 1 (guard offset)
        unsigned long long A = s_chg[cur ^ 1][wlo];
        unsigned long long Bw = s_chg[cur ^ 1][wlo + 1];
        unsigned long long win = sh ? ((A >> sh) | (Bw << (64 - sh))) : A;
        if (win & 0x7Full) {
          unsigned long long u = U[t];
          if (u) {
            unsigned long long wu[9], wk[9];
            #pragma unroll
            for (int j = 0; j < 9; ++j) { wu[j] = U[t - 4 + j]; wk[j] = K[t - 4 + j]; }
            unsigned long long anyK = 0ull, anyU = 0ull;
            #pragma unroll
            for (int b = 0; b < 12; ++b) {
              unsigned long long d = s_D[b][t];
              anyK |= shift_b(wk, b) & d;
              anyU |= shift_b(wu, b) & d;
            }
            unsigned long long u2 = u & anyU & ~anyK;
            if (u2 != u) {
              K[t] = wk[4] | (u & ~anyU & ~anyK);
              U[t] = u2;
              changed = true;
            }
          }
        }
      }
      unsigned long long bb = __ballot(changed);
      if (lane == 0) s_chg[cur][1 + (tid >> 6)] = bb;
    }
    __syncthreads();
    // uniform termination read (broadcast, post-barrier)
    if ((s_chg[cur][1] | s_chg[cur][2] | s_chg[cur][3]) == 0ull) break;
    cur ^= 1;
  }

  // K last written >=2 barriers before the break => visible to all.
  if (tid < NW) keep_out[tid] = K[tid];
}

__global__ __launch_bounds__(NTB) void epi_kernel(
    const float* __restrict__ cls,
    const float* __restrict__ bbox,
    const unsigned long long* __restrict__ keep,
    float* __restrict__ out)
{
  const int n = blockIdx.x * NTB + threadIdx.x;   // grid 36*256 == 9216 exact
  const int r = n / Ww, c = n - r * Ww;
  const float fc = (float)c, fr = (float)r;
  const float x1 = rintf((2.0f * fc) / 0.6f);
  const float x2 = rintf((2.0f * fc + 12.0f) / 0.6f);
  const float y1 = rintf((2.0f * fr) / 0.6f);
  const float y2 = rintf((2.0f * fr + 12.0f) / 0.6f);
  const float k = (float)((keep[n >> 6] >> (n & 63)) & 1ull);  // wave-uniform word
  const float4 reg = reinterpret_cast<const float4*>(bbox)[n];
  const float bbw = x2 - x1 + 1.0f, bbh = y2 - y1 + 1.0f;
  out[n * 5 + 0] = (x1 + reg.x * bbw) * k;
  out[n * 5 + 1] = (y1 + reg.y * bbh) * k;
  out[n * 5 + 2] = (x2 + reg.z * bbw) * k;
  out[n * 5 + 3] = (y2 + reg.w * bbh) * k;
  out[n * 5 + 4] = cls[n] * k;
}

} // namespace

extern "C" void kernel_launch(void* const* d_in, const int* in_sizes, int n_in,
                              void* d_out, int out_size, void* d_ws, size_t ws_size,
                              hipStream_t stream) {
  const float* cls  = (const float*)d_in[0];               // (96,96) f32
  const float* bbox = (const float*)d_in[1];               // (96,96,4) f32
  float* out = (float*)d_out;                              // (9216,5) f32
  unsigned long long* keep = (unsigned long long*)d_ws;    // 144 u64 = 1152 B
  hipLaunchKernelGGL(nms_kernel, dim3(1), dim3(NTA), 0, stream, cls, keep);
  hipLaunchKernelGGL(epi_kernel, dim3(Nn / NTB), dim3(NTB), 0, stream,
                     cls, bbox, keep, out);
}

// Round 5
// 92.786 us; speedup vs baseline: 1.0270x; 1.0270x over previous
//
#include <hip/hip_runtime.h>

// MTCNN proposal stage: score threshold + greedy NMS + bbox regression, 96x96.
//
// Validated-exact facts (R1-R4 passed, absmax 0.0):
//  - All boxes 21x21 (area 441), pitch 3/4/3 (period 3). IoU>0.5 <=> inter>294.
//  - Suppression pairs only at 12 offsets {+-1,+-2 axial, +-1 diagonal} with an
//    index%3 geometry rule => pure bit logic, no float IoU.
//  - Greedy NMS == unique fixpoint of monotone 3-state relaxation over the
//    dominance graph (priority = score desc, index asc; ties on negative
//    offsets use >=). In-place bitboard Jacobi is race-benign.
//
// R5: ONE dispatch (R4 showed ~7-10us wall cost per extra dispatch).
// 1024 threads: 16 waves for the latency-bound stage/mask/epilogue phases.
// Rounds: no gating; per-word D[12] + self U/K held in registers of the 144
// eval threads (write-through to LDS on change); single change flag with the
// validated period-3 rotation. Epilogue: fully-coalesced float4 stores (each
// thread materializes the <=2 cells its float4 spans).

namespace {

constexpr int Hh = 96, Ww = 96, Nn = Hh * Ww;   // 9216
constexpr int NW = Nn / 64;                      // 144 words
constexpr float THR_SCORE = 0.6f;
constexpr int NT = 1024;

// Bit b -> flat offset: {-1,+1,-2,+2,-96,+96,-192,+192,-97,-95,+95,+97}
__device__ __forceinline__ unsigned long long shift_b(const unsigned long long w[9], int b) {
  // result bit i (word t) = bitmap bit (64*t + i + OFF[b]); w[j] = W[t-4+j]
  switch (b) {
    case 0:  return (w[4] << 1)  | (w[3] >> 63);   // -1
    case 1:  return (w[4] >> 1)  | (w[5] << 63);   // +1
    case 2:  return (w[4] << 2)  | (w[3] >> 62);   // -2
    case 3:  return (w[4] >> 2)  | (w[5] << 62);   // +2
    case 4:  return (w[3] << 32) | (w[2] >> 32);   // -96
    case 5:  return (w[5] >> 32) | (w[6] << 32);   // +96
    case 6:  return w[1];                          // -192
    case 7:  return w[7];                          // +192
    case 8:  return (w[3] << 33) | (w[2] >> 31);   // -97
    case 9:  return (w[3] << 31) | (w[2] >> 33);   // -95
    case 10: return (w[5] >> 31) | (w[6] << 33);   // +95
    default: return (w[5] >> 33) | (w[6] << 31);   // +97
  }
}

struct Cell5 { float a, b, c, d, e; };

__device__ __forceinline__ float pick5(const Cell5& s, int j) {
  return j == 0 ? s.a : j == 1 ? s.b : j == 2 ? s.c : j == 3 ? s.d : s.e;
}

__global__ __launch_bounds__(NT) void mtcnn_kernel(
    const float* __restrict__ cls,
    const float* __restrict__ bbox,
    float* __restrict__ out)
{
  __shared__ float s_sc[Nn];                      // staged scores (whole kernel)
  __shared__ unsigned long long s_D[12][NW];      // dominance bitmaps
  __shared__ unsigned long long s_Up[NW + 8];     // UNDEC, 4 guard words/side
  __shared__ unsigned long long s_Kp[NW + 8];     // KEPT
  __shared__ int s_ch[3];                         // period-3 change flags

  unsigned long long* const U = s_Up + 4;
  unsigned long long* const K = s_Kp + 4;

  const int tid = threadIdx.x;
  const int lane = tid & 63;
  const int OFF[12] = {-1, 1, -2, 2, -Ww, Ww, -2*Ww, 2*Ww, -Ww-1, -Ww+1, Ww-1, Ww+1};

  // ---- Phase 1: stage scores, zero guards/flags ----
  for (int q = tid; q < Nn / 4; q += NT)
    reinterpret_cast<float4*>(s_sc)[q] = reinterpret_cast<const float4*>(cls)[q];
  if (tid < 4) {
    s_Up[tid] = 0ull; s_Kp[tid] = 0ull;
    s_Up[4 + NW + tid] = 0ull; s_Kp[4 + NW + tid] = 0ull;
  }
  if (tid < 3) s_ch[tid] = 0;
  __syncthreads();

  // ---- Phase 2: per-cell dominance mask (validated logic) -> ballots ----
  for (int n = tid; n < Nn; n += NT) {
    float si = s_sc[n];
    unsigned int m = 0;
    bool valid = si > THR_SCORE;
    if (valid) {
      int r = n / Ww, c = n - r * Ww;
      int rm = r % 3, cm = c % 3;
      unsigned int geom = (1u << 0) | (1u << 1) | (1u << 4) | (1u << 5);
      if (cm == 1) geom |= 1u << 2;
      if (cm == 2) geom |= 1u << 3;
      if (rm == 1) geom |= 1u << 6;
      if (rm == 2) geom |= 1u << 7;
      if (!(rm == 2 && cm == 2)) geom |= 1u << 8;
      if (!(rm == 2 && cm == 1)) geom |= 1u << 9;
      if (!(rm == 1 && cm == 2)) geom |= 1u << 10;
      if (!(rm == 1 && cm == 1)) geom |= 1u << 11;
      unsigned int inb = 0;
      bool cge1 = c >= 1, cle = c <= Ww - 2, rge1 = r >= 1, rle = r <= Hh - 2;
      if (cge1) inb |= 1u << 0;
      if (cle)  inb |= 1u << 1;
      if (c >= 2)      inb |= 1u << 2;
      if (c <= Ww - 3) inb |= 1u << 3;
      if (rge1) inb |= 1u << 4;
      if (rle)  inb |= 1u << 5;
      if (r >= 2)      inb |= 1u << 6;
      if (r <= Hh - 3) inb |= 1u << 7;
      if (rge1 && cge1) inb |= 1u << 8;
      if (rge1 && cle)  inb |= 1u << 9;
      if (rle && cge1)  inb |= 1u << 10;
      if (rle && cle)   inb |= 1u << 11;
      unsigned int cand = geom & inb;
      #pragma unroll
      for (int b = 0; b < 12; ++b) {
        int j = n + OFF[b];
        j = min(max(j, 0), Nn - 1);
        float sj = s_sc[j];
        bool ge = (b == 0) | (b == 2) | (b == 4) | (b == 6) | (b == 8) | (b == 9);
        bool dom = ge ? (sj >= si) : (sj > si);
        if (((cand >> b) & 1u) && (sj > THR_SCORE) && dom) m |= 1u << b;
      }
    }
    int w = n >> 6;
    #pragma unroll
    for (int b = 0; b < 12; ++b) {
      unsigned long long bb = __ballot((m >> b) & 1u);
      if (lane == 0) s_D[b][w] = bb;
    }
    unsigned long long vb = __ballot(valid);
    if (lane == 0) { U[w] = vb; K[w] = 0ull; }
  }
  __syncthreads();

  // ---- Rounds: bitboard Jacobi; D + self state in registers; 1 barrier/rnd.
  const int t = tid;
  unsigned long long regD[12];
  unsigned long long u_self = 0ull, k_self = 0ull;
  if (t < NW) {
    #pragma unroll
    for (int b = 0; b < 12; ++b) regD[b] = s_D[b][t];
    u_self = U[t];
  }
  for (int it = 0; it < 3000; ++it) {
    const int f = it % 3;
    if (tid == 0) s_ch[(it + 1) % 3] = 0;       // reset next round's flag
    if (t < NW && u_self) {
      unsigned long long wu[9], wk[9];
      #pragma unroll
      for (int j = 0; j < 9; ++j) {
        if (j == 4) continue;
        wu[j] = U[t - 4 + j]; wk[j] = K[t - 4 + j];
      }
      wu[4] = u_self; wk[4] = k_self;
      unsigned long long anyK = 0ull, anyU = 0ull;
      #pragma unroll
      for (int b = 0; b < 12; ++b) {
        anyK |= shift_b(wk, b) & regD[b];
        anyU |= shift_b(wu, b) & regD[b];
      }
      unsigned long long u2 = u_self & anyU & ~anyK;
      if (u2 != u_self) {
        k_self |= u_self & ~anyU & ~anyK;
        u_self = u2;
        U[t] = u_self; K[t] = k_self;           // write-through (sole writer)
        s_ch[f] = 1;                            // benign race: all store 1
      }
    }
    __syncthreads();
    if (s_ch[f] == 0) break;                    // uniform broadcast read
  }
  // K stable: last writes precede the final (no-change) round's barrier.

  // ---- Epilogue: coalesced float4 stores; each f4 spans <=2 cells ----
  const float4* bbox4 = reinterpret_cast<const float4*>(bbox);
  float4* out4 = reinterpret_cast<float4*>(out);
  for (int q = tid; q < (Nn * 5) / 4; q += NT) {
    int e = q * 4;
    int n0 = e / 5;
    int j0 = e - n0 * 5;
    int n1 = (j0 <= 1) ? n0 : (n0 + 1);        // last cell touched <= 9215
    Cell5 v0, v1;
    #pragma unroll
    for (int s = 0; s < 2; ++s) {
      int n = s ? n1 : n0;
      int r = n / Ww, c = n - r * Ww;
      float fc = (float)c, fr = (float)r;
      float x1 = rintf((2.0f * fc) / 0.6f);
      float x2 = rintf((2.0f * fc + 12.0f) / 0.6f);
      float y1 = rintf((2.0f * fr) / 0.6f);
      float y2 = rintf((2.0f * fr + 12.0f) / 0.6f);
      float k = (float)((K[n >> 6] >> (n & 63)) & 1ull);
      float4 reg = bbox4[n];
      float bw = x2 - x1 + 1.0f, bh = y2 - y1 + 1.0f;
      Cell5 v;
      v.a = (x1 + reg.x * bw) * k;
      v.b = (y1 + reg.y * bh) * k;
      v.c = (x2 + reg.z * bw) * k;
      v.d = (y2 + reg.w * bh) * k;
      v.e = s_sc[n] * k;
      if (s) v1 = v; else v0 = v;
    }
    float4 o;
    o.x = (j0 + 0 < 5) ? pick5(v0, j0 + 0) : pick5(v1, j0 - 5);
    o.y = (j0 + 1 < 5) ? pick5(v0, j0 + 1) : pick5(v1, j0 - 4);
    o.z = (j0 + 2 < 5) ? pick5(v0, j0 + 2) : pick5(v1, j0 - 3);
    o.w = (j0 + 3 < 5) ? pick5(v0, j0 + 3) : pick5(v1, j0 - 2);
    out4[q] = o;
  }
}

} // namespace

extern "C" void kernel_launch(void* const* d_in, const int* in_sizes, int n_in,
                              void* d_out, int out_size, void* d_ws, size_t ws_size,
                              hipStream_t stream) {
  const float* cls  = (const float*)d_in[0];   // (96,96) f32
  const float* bbox = (const float*)d_in[1];   // (96,96,4) f32
  float* out = (float*)d_out;                  // (9216,5) f32
  hipLaunchKernelGGL(mtcnn_kernel, dim3(1), dim3(NT), 0, stream, cls, bbox, out);
}

// Round 6
// 78.692 us; speedup vs baseline: 1.2110x; 1.1791x over previous
//
#include <hip/hip_runtime.h>

// MTCNN proposal stage: score threshold + greedy NMS + bbox regression, 96x96.
//
// Validated-exact facts (R1-R5 passed, absmax 0.0):
//  - All boxes 21x21 (area 441), pitch 3/4/3 (period 3). IoU>0.5 <=> inter>294.
//  - Suppression pairs only at 12 offsets {+-1,+-2 axial, +-1 diagonal} with an
//    index%3 geometry rule => pure bit logic, no float IoU.
//  - Greedy NMS == unique fixpoint of monotone 3-state relaxation over the
//    dominance graph (priority = score desc, index asc; ties on negative
//    offsets use >=). In-place bitboard Jacobi is race-benign.
//
// R6: hide the serial 144 KB bbox read (the suspected ~15-25us hidden cost
// behind the 42us plateau of R3/R4/R5) under mask-build + rounds:
//  - prefetch bbox into 36 VGPRs/thread right after phase 1;
//  - all later barriers are LDS-ONLY (fence("workgroup","local") + s_barrier)
//    so no vmcnt(0) drain re-serializes the prefetch (rounds touch only LDS);
//  - sched_barrier(0) pins the prefetch issue point;
//  - epilogue consumes the registers, per-cell stores (wave covers 1280 B
//    contiguous per store group).

namespace {

constexpr int Hh = 96, Ww = 96, Nn = Hh * Ww;   // 9216
constexpr int NW = Nn / 64;                      // 144 words
constexpr float THR_SCORE = 0.6f;
constexpr int NT = 1024;
constexpr int CPT = Nn / NT;                     // 9 cells/thread

typedef float v4a __attribute__((ext_vector_type(4), aligned(4)));

// LDS-only barrier: s_waitcnt lgkmcnt(0) + s_barrier; leaves vmcnt untouched.
__device__ __forceinline__ void lds_barrier() {
  __builtin_amdgcn_fence(__ATOMIC_RELEASE, "workgroup", "local");
  __builtin_amdgcn_s_barrier();
  __builtin_amdgcn_fence(__ATOMIC_ACQUIRE, "workgroup", "local");
}

// Bit b -> flat offset: {-1,+1,-2,+2,-96,+96,-192,+192,-97,-95,+95,+97}
__device__ __forceinline__ unsigned long long shift_b(const unsigned long long w[9], int b) {
  // result bit i (word t) = bitmap bit (64*t + i + OFF[b]); w[j] = W[t-4+j]
  switch (b) {
    case 0:  return (w[4] << 1)  | (w[3] >> 63);   // -1
    case 1:  return (w[4] >> 1)  | (w[5] << 63);   // +1
    case 2:  return (w[4] << 2)  | (w[3] >> 62);   // -2
    case 3:  return (w[4] >> 2)  | (w[5] << 62);   // +2
    case 4:  return (w[3] << 32) | (w[2] >> 32);   // -96
    case 5:  return (w[5] >> 32) | (w[6] << 32);   // +96
    case 6:  return w[1];                          // -192
    case 7:  return w[7];                          // +192
    case 8:  return (w[3] << 33) | (w[2] >> 31);   // -97
    case 9:  return (w[3] << 31) | (w[2] >> 33);   // -95
    case 10: return (w[5] >> 31) | (w[6] << 33);   // +95
    default: return (w[5] >> 33) | (w[6] << 31);   // +97
  }
}

__global__ __launch_bounds__(NT) void mtcnn_kernel(
    const float* __restrict__ cls,
    const float* __restrict__ bbox,
    float* __restrict__ out)
{
  __shared__ float s_sc[Nn];                      // staged scores (whole kernel)
  __shared__ unsigned long long s_D[12][NW];      // dominance bitmaps
  __shared__ unsigned long long s_Up[NW + 8];     // UNDEC, 4 guard words/side
  __shared__ unsigned long long s_Kp[NW + 8];     // KEPT
  __shared__ int s_ch[3];                         // period-3 change flags

  unsigned long long* const U = s_Up + 4;
  unsigned long long* const K = s_Kp + 4;

  const int tid = threadIdx.x;
  const int lane = tid & 63;
  const int OFF[12] = {-1, 1, -2, 2, -Ww, Ww, -2*Ww, 2*Ww, -Ww-1, -Ww+1, Ww-1, Ww+1};

  // ---- Phase 1: stage scores, zero guards/flags ----
  for (int q = tid; q < Nn / 4; q += NT)
    reinterpret_cast<float4*>(s_sc)[q] = reinterpret_cast<const float4*>(cls)[q];
  if (tid < 4) {
    s_Up[tid] = 0ull; s_Kp[tid] = 0ull;
    s_Up[4 + NW + tid] = 0ull; s_Kp[4 + NW + tid] = 0ull;
  }
  if (tid < 3) s_ch[tid] = 0;
  lds_barrier();

  // ---- Prefetch bbox into registers; stays in flight through phase 2+rounds
  v4a bb[CPT];
  {
    const v4a* bbox4 = reinterpret_cast<const v4a*>(bbox);
    #pragma unroll
    for (int i = 0; i < CPT; ++i) bb[i] = bbox4[tid + i * NT];
  }
  __builtin_amdgcn_sched_barrier(0);   // pin issue point; don't sink loads

  // ---- Phase 2: per-cell dominance mask (validated logic) -> ballots ----
  for (int n = tid; n < Nn; n += NT) {
    float si = s_sc[n];
    unsigned int m = 0;
    bool valid = si > THR_SCORE;
    if (valid) {
      int r = n / Ww, c = n - r * Ww;
      int rm = r % 3, cm = c % 3;
      unsigned int geom = (1u << 0) | (1u << 1) | (1u << 4) | (1u << 5);
      if (cm == 1) geom |= 1u << 2;
      if (cm == 2) geom |= 1u << 3;
      if (rm == 1) geom |= 1u << 6;
      if (rm == 2) geom |= 1u << 7;
      if (!(rm == 2 && cm == 2)) geom |= 1u << 8;
      if (!(rm == 2 && cm == 1)) geom |= 1u << 9;
      if (!(rm == 1 && cm == 2)) geom |= 1u << 10;
      if (!(rm == 1 && cm == 1)) geom |= 1u << 11;
      unsigned int inb = 0;
      bool cge1 = c >= 1, cle = c <= Ww - 2, rge1 = r >= 1, rle = r <= Hh - 2;
      if (cge1) inb |= 1u << 0;
      if (cle)  inb |= 1u << 1;
      if (c >= 2)      inb |= 1u << 2;
      if (c <= Ww - 3) inb |= 1u << 3;
      if (rge1) inb |= 1u << 4;
      if (rle)  inb |= 1u << 5;
      if (r >= 2)      inb |= 1u << 6;
      if (r <= Hh - 3) inb |= 1u << 7;
      if (rge1 && cge1) inb |= 1u << 8;
      if (rge1 && cle)  inb |= 1u << 9;
      if (rle && cge1)  inb |= 1u << 10;
      if (rle && cle)   inb |= 1u << 11;
      unsigned int cand = geom & inb;
      #pragma unroll
      for (int b = 0; b < 12; ++b) {
        int j = n + OFF[b];
        j = min(max(j, 0), Nn - 1);
        float sj = s_sc[j];
        bool ge = (b == 0) | (b == 2) | (b == 4) | (b == 6) | (b == 8) | (b == 9);
        bool dom = ge ? (sj >= si) : (sj > si);
        if (((cand >> b) & 1u) && (sj > THR_SCORE) && dom) m |= 1u << b;
      }
    }
    int w = n >> 6;
    #pragma unroll
    for (int b = 0; b < 12; ++b) {
      unsigned long long bb2 = __ballot((m >> b) & 1u);
      if (lane == 0) s_D[b][w] = bb2;
    }
    unsigned long long vb = __ballot(valid);
    if (lane == 0) { U[w] = vb; K[w] = 0ull; }
  }
  lds_barrier();

  // ---- Rounds: bitboard Jacobi; D + self state in registers; LDS-only
  //      barrier per round (keeps bbox loads in flight).
  const int t = tid;
  unsigned long long regD[12];
  unsigned long long u_self = 0ull, k_self = 0ull;
  if (t < NW) {
    #pragma unroll
    for (int b = 0; b < 12; ++b) regD[b] = s_D[b][t];
    u_self = U[t];
  }
  for (int it = 0; it < 3000; ++it) {
    const int f = it % 3;
    if (tid == 0) s_ch[(it + 1) % 3] = 0;       // reset next round's flag
    if (t < NW && u_self) {
      unsigned long long wu[9], wk[9];
      #pragma unroll
      for (int j = 0; j < 9; ++j) {
        if (j == 4) continue;
        wu[j] = U[t - 4 + j]; wk[j] = K[t - 4 + j];
      }
      wu[4] = u_self; wk[4] = k_self;
      unsigned long long anyK = 0ull, anyU = 0ull;
      #pragma unroll
      for (int b = 0; b < 12; ++b) {
        anyK |= shift_b(wk, b) & regD[b];
        anyU |= shift_b(wu, b) & regD[b];
      }
      unsigned long long u2 = u_self & anyU & ~anyK;
      if (u2 != u_self) {
        k_self |= u_self & ~anyU & ~anyK;
        u_self = u2;
        U[t] = u_self; K[t] = k_self;           // write-through (sole writer)
        s_ch[f] = 1;                            // benign race: all store 1
      }
    }
    lds_barrier();
    if (s_ch[f] == 0) break;                    // uniform broadcast read
  }
  // K stable: last K writes precede the final (no-change) round's barrier.

  // ---- Epilogue: per-cell from prefetched registers ----
  #pragma unroll
  for (int i = 0; i < CPT; ++i) {
    int n = tid + i * NT;
    int r = n / Ww, c = n - r * Ww;
    float fc = (float)c, fr = (float)r;
    float x1 = rintf((2.0f * fc) / 0.6f);
    float x2 = rintf((2.0f * fc + 12.0f) / 0.6f);
    float y1 = rintf((2.0f * fr) / 0.6f);
    float y2 = rintf((2.0f * fr + 12.0f) / 0.6f);
    float k = (float)((K[n >> 6] >> (n & 63)) & 1ull);
    v4a reg = bb[i];
    float bw = x2 - x1 + 1.0f, bh = y2 - y1 + 1.0f;
    v4a o;
    o.x = (x1 + reg.x * bw) * k;
    o.y = (y1 + reg.y * bh) * k;
    o.z = (x2 + reg.z * bw) * k;
    o.w = (y2 + reg.w * bh) * k;
    *reinterpret_cast<v4a*>(out + n * 5) = o;
    out[n * 5 + 4] = s_sc[n] * k;
  }
}

} // namespace

extern "C" void kernel_launch(void* const* d_in, const int* in_sizes, int n_in,
                              void* d_out, int out_size, void* d_ws, size_t ws_size,
                              hipStream_t stream) {
  const float* cls  = (const float*)d_in[0];   // (96,96) f32
  const float* bbox = (const float*)d_in[1];   // (96,96,4) f32
  float* out = (float*)d_out;                  // (9216,5) f32
  hipLaunchKernelGGL(mtcnn_kernel, dim3(1), dim3(NT), 0, stream, cls, bbox, out);
}